// Round 5
// baseline (287.209 us; speedup 1.0000x reference)
//
#include <hip/hip_runtime.h>

// Problem constants (fixed by setup_inputs)
#define B_SZ   8192
#define CH     5120          // C*H = 20*256
#define CH4    1280          // CH / 4 (float4 columns per row)
#define K_LAB  10
#define EPS    1e-8f
#define FLTMAX 3.402823466e38f

// Pass-1 tiling: 256 row-chunks x 4 col-chunks = 1024 blocks (3/CU resident)
#define RC_N   256           // row chunks
#define ROWS   32            // rows per chunk (RC_N*ROWS == B_SZ)
#define CC_N   4             // col chunks
#define CCW    320           // float4 columns per col chunk (CC_N*CCW == CH4)
#define NT1    320           // 5 waves
#define NPF    4             // prefetch depth per ping-pong buffer
#define NFOLD  (K_LAB * CC_N)           // 40 fold blocks (k, cc)

// loss = sum_{k: n_k>0} (SSQ_k - ||S_k||^2/n_k + n_k*CH*eps^2) / (n_k*CH)
// (2*eps cross-term cancels exactly: sum_{b in k}(z_b - mu_k) == 0)

__device__ __forceinline__ float4 sanitize(float4 v) {
    v.x = (v.x == v.x) ? fminf(fmaxf(v.x, -FLTMAX), FLTMAX) : 0.f;
    v.y = (v.y == v.y) ? fminf(fmaxf(v.y, -FLTMAX), FLTMAX) : 0.f;
    v.z = (v.z == v.z) ? fminf(fmaxf(v.z, -FLTMAX), FLTMAX) : 0.f;
    v.w = (v.w == v.w) ? fminf(fmaxf(v.w, -FLTMAX), FLTMAX) : 0.f;
    return v;
}

// ---------------------------------------------------------------------------
// Pass 1: stream z contiguously; wave-uniform switch accumulate (R4: fixed
// VALU); 4+4 ping-pong prefetch + 1024-block grid attack R4's measured
// latency-boundedness (99 us @ 14% BW, 13% occupancy, 10 waves/CU).
// NO __launch_bounds__ min-waves: R3 showed (NT1,5) forces VGPR=48 + spills.
__global__ __launch_bounds__(NT1) void codi_pass1(
    const float4* __restrict__ z4, const int* __restrict__ labels,
    float4* __restrict__ P_sum, float* __restrict__ P_ssq,
    int* __restrict__ P_cnt, int* __restrict__ done)
{
    const int tid = threadIdx.x;
    const int rc  = blockIdx.x >> 2;     // row-chunk
    const int cc  = blockIdx.x & 3;      // col-chunk

    __shared__ int   lab_s[ROWS];
    __shared__ float wssq[5][K_LAB];

    if (blockIdx.x == 0 && tid == 0) *done = 0;   // re-init ticket (poisoned ws)

    if (tid < ROWS) lab_s[tid] = labels[rc * ROWS + tid];
    __syncthreads();

    float4 sum[K_LAB];
    float  ssq[K_LAB];
    #pragma unroll
    for (int k = 0; k < K_LAB; ++k) {
        sum[k] = make_float4(0.f, 0.f, 0.f, 0.f);
        ssq[k] = 0.f;
    }

    // thread owns one float4 column; rows are contiguous -> pure streaming
    const float4* zp = z4 + (size_t)rc * ROWS * CH4 + cc * CCW + tid;

    #define LD(BUF, R0) do { \
        _Pragma("unroll") \
        for (int u = 0; u < NPF; ++u) BUF[u] = zp[(size_t)((R0) + u) * CH4]; \
    } while (0)

    #define EAT(BUF, R0) do { \
        _Pragma("unroll") \
        for (int u = 0; u < NPF; ++u) { \
            const int lab = __builtin_amdgcn_readfirstlane(lab_s[(R0) + u]); \
            float4 t = sanitize(BUF[u]); \
            float  q = fmaf(t.x, t.x, fmaf(t.y, t.y, fmaf(t.z, t.z, t.w * t.w))); \
            switch (lab) {   /* wave-uniform s_cbranch tree: 5 adds/row */ \
                case 0: ACC(0); break;  case 1: ACC(1); break; \
                case 2: ACC(2); break;  case 3: ACC(3); break; \
                case 4: ACC(4); break;  case 5: ACC(5); break; \
                case 6: ACC(6); break;  case 7: ACC(7); break; \
                case 8: ACC(8); break;  default: ACC(9); break; \
            } \
        } \
    } while (0)

    #define ACC(K) do { \
        sum[K].x += t.x; sum[K].y += t.y; \
        sum[K].z += t.z; sum[K].w += t.w; ssq[K] += q; } while (0)

    // ping-pong: issue B's loads before consuming A -> ~8 loads always in
    // flight; compiler emits counted vmcnt so compute overlaps the tail.
    float4 va[NPF], vb[NPF];
    LD(va, 0);
    for (int r = 0; r < ROWS; r += 2 * NPF) {       // 4 iterations, uniform
        LD(vb, r + NPF);
        EAT(va, r);
        if (r + 2 * NPF < ROWS) LD(va, r + 2 * NPF);
        EAT(vb, r + NPF);
    }
    #undef ACC
    #undef EAT
    #undef LD

    // per-label partial row-sums, [k][cc][rc][col]: coalesced 5 KB stores,
    // pass-2's rc-fold is then a sequential stream (R3's transpose, proven)
    #pragma unroll
    for (int k = 0; k < K_LAB; ++k)
        P_sum[(((size_t)(k * CC_N + cc)) * RC_N + rc) * CCW + tid] = sum[k];

    // block-reduce ssq[k] -> P_ssq[(rc*4+cc)*10 + k]
    const int lane = tid & 63, wid = tid >> 6;
    #pragma unroll
    for (int k = 0; k < K_LAB; ++k) {
        float s = ssq[k];
        #pragma unroll
        for (int o = 32; o > 0; o >>= 1) s += __shfl_down(s, o, 64);
        if (lane == 0) wssq[wid][k] = s;
    }
    __syncthreads();
    if (tid < K_LAB)
        P_ssq[(rc * CC_N + cc) * K_LAB + tid] =
            wssq[0][tid] + wssq[1][tid] + wssq[2][tid] + wssq[3][tid] + wssq[4][tid];

    // per-chunk label counts (one writer: cc==0, wave 0, 10 ballots)
    if (cc == 0 && tid < 64) {
        const int lab = (tid < ROWS) ? lab_s[tid] : -1;
        #pragma unroll
        for (int k = 0; k < K_LAB; ++k) {
            unsigned long long m = __ballot(lab == k);
            if (tid == k) P_cnt[rc * K_LAB + k] = __popcll(m);
        }
    }
}

// ---------------------------------------------------------------------------
// Pass 2: 40 blocks (k, cc); each streams its 1.3 MB [rc][col] panel
// sequentially (L2/L3-hot), folds to ||S_k||^2 partials; fcc==0 blocks fold
// SSQ_k and n_k; last-ticket block finalizes the loss.
__global__ __launch_bounds__(NT1) void codi_pass2(
    const float4* __restrict__ P_sum, const float* __restrict__ P_ssq,
    const int* __restrict__ P_cnt, float* __restrict__ pn,
    float* __restrict__ ssqk, float* __restrict__ cntk,
    int* __restrict__ done, float* __restrict__ out)
{
    const int tid  = threadIdx.x;
    const int lane = tid & 63, wid = tid >> 6;
    const int fid  = blockIdx.x;         // 0..39
    const int fk   = fid >> 2, fcc = fid & 3;

    __shared__ float red_q[5], red_s[5];
    __shared__ int   red_n[5];
    __shared__ int   tkt;

    // col-sum over rc: block walks 256 x 5 KB sequentially
    const float4* p = P_sum + ((size_t)(fk * CC_N + fcc) * RC_N) * CCW + tid;
    float4 s4 = make_float4(0.f, 0.f, 0.f, 0.f);
    #pragma unroll 8
    for (int rc = 0; rc < RC_N; ++rc) {
        float4 v = p[(size_t)rc * CCW];
        s4.x += v.x; s4.y += v.y; s4.z += v.z; s4.w += v.w;
    }
    float q = fmaf(s4.x, s4.x, fmaf(s4.y, s4.y, fmaf(s4.z, s4.z, s4.w * s4.w)));
    #pragma unroll
    for (int o = 32; o > 0; o >>= 1) q += __shfl_down(q, o, 64);

    // SSQ_k and n_k folds (only the fcc==0 block of each k)
    float s2 = 0.f;
    int   n  = 0;
    if (fcc == 0) {
        for (int i = tid; i < RC_N * CC_N; i += NT1) s2 += P_ssq[i * K_LAB + fk];
        if (tid < RC_N) n = P_cnt[tid * K_LAB + fk];
    }
    #pragma unroll
    for (int o = 32; o > 0; o >>= 1) s2 += __shfl_down(s2, o, 64);
    #pragma unroll
    for (int o = 32; o > 0; o >>= 1) n += __shfl_down(n, o, 64);

    if (lane == 0) { red_q[wid] = q; red_s[wid] = s2; red_n[wid] = n; }
    __syncthreads();
    if (tid == 0) {
        pn[fid] = red_q[0] + red_q[1] + red_q[2] + red_q[3] + red_q[4];
        if (fcc == 0) {
            ssqk[fk] = red_s[0] + red_s[1] + red_s[2] + red_s[3] + red_s[4];
            cntk[fk] = (float)(red_n[0] + red_n[1] + red_n[2] + red_n[3] + red_n[4]);
        }
    }

    // ---------------- finalize: last block computes the loss
    __threadfence();
    __syncthreads();
    if (tid == 0) tkt = atomicAdd(done, 1);   // tickets 0..39
    __syncthreads();
    if (tkt == NFOLD - 1 && tid < 64) {
        float np4 = (tid < NFOLD) ? atomicAdd(&pn[tid], 0.f) : 0.f;   // coherent
        np4 += __shfl_down(np4, 2, 64);
        np4 += __shfl_down(np4, 1, 64);   // lane 4k holds sum over cc
        float s2v = (tid < K_LAB) ? atomicAdd(&ssqk[tid], 0.f) : 0.f;
        float nnv = (tid < K_LAB) ? atomicAdd(&cntk[tid], 0.f) : 0.f;
        float acc = 0.f;
        for (int k = 0; k < K_LAB; ++k) {
            float np = __shfl(np4, 4 * k, 64);
            float sk = __shfl(s2v, k, 64);
            float nk = __shfl(nnv, k, 64);
            if (nk > 0.f) {
                float sse = sk - np / nk + nk * (float)CH * (EPS * EPS);
                float mse = sse / (nk * (float)CH);
                if (mse == mse) acc += mse;    // nan_to_num(mse_k)
            }
        }
        if (tid == 0) out[0] = acc;
    }
}

// ---------------------------------------------------------------------------
extern "C" void kernel_launch(void* const* d_in, const int* in_sizes, int n_in,
                              void* d_out, int out_size, void* d_ws, size_t ws_size,
                              hipStream_t stream) {
    const float4* z4     = (const float4*)d_in[0];
    const int*    labels = (const int*)d_in[1];

    // ws layout (float units):
    //   [0] done (int) | [16..56) pn[40] | [64..74) ssqk | [80..90) cntk
    //   [96..2656) P_cnt[2560] (int) | [2688..12928) P_ssq[10240]
    //   [13056..) P_sum: 10*4*256*320 float4 (byte off 52224, 16B-aligned)
    float*  hdr   = (float*)d_ws;
    int*    done  = (int*)hdr;
    float*  pn    = hdr + 16;
    float*  ssqk  = hdr + 64;
    float*  cntk  = hdr + 80;
    int*    P_cnt = (int*)(hdr + 96);
    float*  P_ssq = hdr + 2688;
    float4* P_sum = (float4*)(hdr + 13056);

    codi_pass1<<<RC_N * CC_N, NT1, 0, stream>>>(z4, labels, P_sum, P_ssq, P_cnt, done);
    codi_pass2<<<NFOLD, NT1, 0, stream>>>(P_sum, P_ssq, P_cnt, pn, ssqk,
                                          cntk, done, (float*)d_out);
}

// Round 7
// 267.496 us; speedup vs baseline: 1.0737x; 1.0737x over previous
//
#include <hip/hip_runtime.h>

// Problem constants (fixed by setup_inputs)
#define B_SZ   8192
#define CH     5120          // C*H = 20*256
#define CH4    1280          // CH / 4 (float4 columns per row)
#define K_LAB  10
#define EPS    1e-8f
#define FLTMAX 3.402823466e38f

// Pass-1 tiling: 256 row-chunks x 4 col-chunks = 1024 blocks.
// P_sum = 52 MB: same workspace footprint as R5 (proven to fit; R6's 105 MB
// doubled it and the container died -> suspected OOB on d_ws).
#define RC_N   256           // row chunks
#define ROWS   32            // rows per chunk (RC_N*ROWS == B_SZ)
#define CC_N   4             // col chunks
#define CCW    320           // float4 columns per col chunk (CC_N*CCW == CH4)
#define NT1    320           // 5 waves
#define NPF    4             // prefetch depth per ping-pong buffer
#define NFOLD  (K_LAB * CC_N)           // 40 fold blocks (k, cc)

// loss = sum_{k: n_k>0} (SSQ_k - ||S_k||^2/n_k + n_k*CH*eps^2) / (n_k*CH)
// (2*eps cross-term cancels exactly: sum_{b in k}(z_b - mu_k) == 0)

__device__ __forceinline__ float4 sanitize(float4 v) {
    v.x = (v.x == v.x) ? fminf(fmaxf(v.x, -FLTMAX), FLTMAX) : 0.f;
    v.y = (v.y == v.y) ? fminf(fmaxf(v.y, -FLTMAX), FLTMAX) : 0.f;
    v.z = (v.z == v.z) ? fminf(fmaxf(v.z, -FLTMAX), FLTMAX) : 0.f;
    v.w = (v.w == v.w) ? fminf(fmaxf(v.w, -FLTMAX), FLTMAX) : 0.f;
    return v;
}

// ---------------------------------------------------------------------------
// Pass 1: rows of the chunk are pre-sorted by label (ballot pass, wave 0),
// then processed group-by-group. Only ONE label accumulator is live at a
// time -> ~9 regs of state instead of 50 (R3-R5's occupancy cap), and the
// inner loop has ZERO per-element branches (group boundary = rare uniform
// while). Each group flushes its 16B partial to the transposed P_sum slot.
// NO __launch_bounds__ min-waves: R3 showed forcing it causes spills.
__global__ __launch_bounds__(NT1) void codi_pass1(
    const float4* __restrict__ z4, const int* __restrict__ labels,
    float4* __restrict__ P_sum, float* __restrict__ P_ssq,
    int* __restrict__ P_cnt, int* __restrict__ done)
{
    const int tid  = threadIdx.x;
    const int lane = tid & 63, wid = tid >> 6;
    const int rc   = blockIdx.x >> 2;    // row-chunk
    const int cc   = blockIdx.x & 3;     // col-chunk

    __shared__ int   perm_s[ROWS];       // rows in label-grouped ascending order
    __shared__ int   starts_s[K_LAB + 1];
    __shared__ float wssq[5][K_LAB];

    if (blockIdx.x == 0 && tid == 0) *done = 0;   // re-init ticket (poisoned ws)
    if (tid < 5 * K_LAB) ((float*)wssq)[tid] = 0.f;

    // wave 0: label-grouped ascending row order + group starts (ballot trick)
    if (tid < 64) {
        const int lab = (tid < ROWS) ? labels[rc * ROWS + tid] : -1;
        const unsigned long long ltm = (1ULL << lane) - 1ULL;
        int base = 0;
        #pragma unroll
        for (int k = 0; k < K_LAB; ++k) {
            unsigned long long m = __ballot(lab == k);
            int cnt = __popcll(m);
            if (tid == k) {
                starts_s[k] = base;
                if (cc == 0) P_cnt[rc * K_LAB + k] = cnt;
            }
            if (lab == k) perm_s[base + __popcll(m & ltm)] = tid;
            base += cnt;
        }
        if (tid == 0) starts_s[K_LAB] = ROWS;
    }
    __syncthreads();

    // thread owns one float4 column; rows visited in label-grouped order
    const float4* zp  = z4 + (size_t)rc * ROWS * CH4 + cc * CCW + tid;
    float4*       psb = P_sum + ((size_t)cc * RC_N + rc) * CCW + tid;  // k=0 slot

    float4 cs = make_float4(0.f, 0.f, 0.f, 0.f);   // current group's sum
    float  cq = 0.f;                               // current group's ssq
    int    kcur = 0;
    int    nb   = starts_s[1];                     // next group boundary

    #define FLUSH() do { \
        psb[(size_t)kcur * (CC_N * RC_N * CCW)] = cs; \
        float qq = cq; \
        _Pragma("unroll") \
        for (int o = 32; o > 0; o >>= 1) qq += __shfl_down(qq, o, 64); \
        if (lane == 0) wssq[wid][kcur] += qq; \
        cs = make_float4(0.f, 0.f, 0.f, 0.f); cq = 0.f; \
    } while (0)

    #define LDP(BUF, I0) do { \
        _Pragma("unroll") \
        for (int u = 0; u < NPF; ++u) \
            BUF[u] = zp[(size_t)perm_s[(I0) + u] * CH4]; \
    } while (0)

    #define CONS(BUF, I0) do { \
        _Pragma("unroll") \
        for (int u = 0; u < NPF; ++u) { \
            while ((I0) + u >= nb) {          /* uniform, ~10 takes per block */ \
                FLUSH(); ++kcur; nb = starts_s[kcur + 1]; \
            } \
            float4 t = sanitize(BUF[u]); \
            float  q = fmaf(t.x, t.x, fmaf(t.y, t.y, fmaf(t.z, t.z, t.w * t.w))); \
            cs.x += t.x; cs.y += t.y; cs.z += t.z; cs.w += t.w; cq += q; \
        } } while (0)

    // ping-pong: B's loads issued before consuming A -> ~8 loads in flight
    float4 va[NPF], vb[NPF];
    LDP(va, 0);
    for (int i = 0; i < ROWS; i += 2 * NPF) {      // 4 iterations, uniform
        LDP(vb, i + NPF);
        CONS(va, i);
        if (i + 2 * NPF < ROWS) LDP(va, i + 2 * NPF);
        CONS(vb, i + NPF);
    }
    for (; kcur < K_LAB; ++kcur) FLUSH();          // trailing (incl. empty) groups
    #undef CONS
    #undef LDP
    #undef FLUSH

    __syncthreads();
    if (tid < K_LAB)
        P_ssq[(rc * CC_N + cc) * K_LAB + tid] =
            wssq[0][tid] + wssq[1][tid] + wssq[2][tid] + wssq[3][tid] + wssq[4][tid];
}

// ---------------------------------------------------------------------------
// Pass 2: 40 blocks (k, cc); each streams its 1.3 MB [rc][col] panel
// sequentially (L2/L3-hot), folds to ||S_k||^2 partials; fcc==0 blocks fold
// SSQ_k and n_k; last-ticket block finalizes the loss.
__global__ __launch_bounds__(NT1) void codi_pass2(
    const float4* __restrict__ P_sum, const float* __restrict__ P_ssq,
    const int* __restrict__ P_cnt, float* __restrict__ pn,
    float* __restrict__ ssqk, float* __restrict__ cntk,
    int* __restrict__ done, float* __restrict__ out)
{
    const int tid  = threadIdx.x;
    const int lane = tid & 63, wid = tid >> 6;
    const int fid  = blockIdx.x;         // 0..39
    const int fk   = fid >> 2, fcc = fid & 3;

    __shared__ float red_q[5], red_s[5];
    __shared__ int   red_n[5];
    __shared__ int   tkt;

    // col-sum over rc: block walks 256 x 5 KB sequentially
    const float4* p = P_sum + ((size_t)(fk * CC_N + fcc) * RC_N) * CCW + tid;
    float4 s4 = make_float4(0.f, 0.f, 0.f, 0.f);
    #pragma unroll 8
    for (int rc = 0; rc < RC_N; ++rc) {
        float4 v = p[(size_t)rc * CCW];
        s4.x += v.x; s4.y += v.y; s4.z += v.z; s4.w += v.w;
    }
    float q = fmaf(s4.x, s4.x, fmaf(s4.y, s4.y, fmaf(s4.z, s4.z, s4.w * s4.w)));
    #pragma unroll
    for (int o = 32; o > 0; o >>= 1) q += __shfl_down(q, o, 64);

    // SSQ_k and n_k folds (only the fcc==0 block of each k)
    float s2 = 0.f;
    int   n  = 0;
    if (fcc == 0) {
        for (int i = tid; i < RC_N * CC_N; i += NT1) s2 += P_ssq[i * K_LAB + fk];
        if (tid < RC_N) n = P_cnt[tid * K_LAB + fk];
    }
    #pragma unroll
    for (int o = 32; o > 0; o >>= 1) s2 += __shfl_down(s2, o, 64);
    #pragma unroll
    for (int o = 32; o > 0; o >>= 1) n += __shfl_down(n, o, 64);

    if (lane == 0) { red_q[wid] = q; red_s[wid] = s2; red_n[wid] = n; }
    __syncthreads();
    if (tid == 0) {
        pn[fid] = red_q[0] + red_q[1] + red_q[2] + red_q[3] + red_q[4];
        if (fcc == 0) {
            ssqk[fk] = red_s[0] + red_s[1] + red_s[2] + red_s[3] + red_s[4];
            cntk[fk] = (float)(red_n[0] + red_n[1] + red_n[2] + red_n[3] + red_n[4]);
        }
    }

    // ---------------- finalize: last block computes the loss
    __threadfence();
    __syncthreads();
    if (tid == 0) tkt = atomicAdd(done, 1);   // tickets 0..39
    __syncthreads();
    if (tkt == NFOLD - 1 && tid < 64) {
        float np4 = (tid < NFOLD) ? atomicAdd(&pn[tid], 0.f) : 0.f;   // coherent
        np4 += __shfl_down(np4, 2, 64);
        np4 += __shfl_down(np4, 1, 64);   // lane 4k holds sum over cc
        float s2v = (tid < K_LAB) ? atomicAdd(&ssqk[tid], 0.f) : 0.f;
        float nnv = (tid < K_LAB) ? atomicAdd(&cntk[tid], 0.f) : 0.f;
        float acc = 0.f;
        for (int k = 0; k < K_LAB; ++k) {
            float np = __shfl(np4, 4 * k, 64);
            float sk = __shfl(s2v, k, 64);
            float nk = __shfl(nnv, k, 64);
            if (nk > 0.f) {
                float sse = sk - np / nk + nk * (float)CH * (EPS * EPS);
                float mse = sse / (nk * (float)CH);
                if (mse == mse) acc += mse;    // nan_to_num(mse_k)
            }
        }
        if (tid == 0) out[0] = acc;
    }
}

// ---------------------------------------------------------------------------
extern "C" void kernel_launch(void* const* d_in, const int* in_sizes, int n_in,
                              void* d_out, int out_size, void* d_ws, size_t ws_size,
                              hipStream_t stream) {
    const float4* z4     = (const float4*)d_in[0];
    const int*    labels = (const int*)d_in[1];

    // ws layout (float units) — identical footprint to R5 (proven to fit):
    //   [0] done (int) | [16..56) pn[40] | [64..74) ssqk | [80..90) cntk
    //   [96..2656) P_cnt[2560] (int) | [2688..12928) P_ssq[10240]
    //   [13056..) P_sum: 10*4*256*320 float4 (byte off 52224, 16B-aligned)
    float*  hdr   = (float*)d_ws;
    int*    done  = (int*)hdr;
    float*  pn    = hdr + 16;
    float*  ssqk  = hdr + 64;
    float*  cntk  = hdr + 80;
    int*    P_cnt = (int*)(hdr + 96);
    float*  P_ssq = hdr + 2688;
    float4* P_sum = (float4*)(hdr + 13056);

    codi_pass1<<<RC_N * CC_N, NT1, 0, stream>>>(z4, labels, P_sum, P_ssq, P_cnt, done);
    codi_pass2<<<NFOLD, NT1, 0, stream>>>(P_sum, P_ssq, P_cnt, pn, ssqk,
                                          cntk, done, (float*)d_out);
}

// Round 8
// 266.552 us; speedup vs baseline: 1.0775x; 1.0035x over previous
//
#include <hip/hip_runtime.h>

// Problem constants (fixed by setup_inputs)
#define B_SZ   8192
#define CH     5120          // C*H = 20*256
#define CH4    1280          // CH / 4 (float4 columns per row)
#define K_LAB  10
#define EPS    1e-8f
#define FLTMAX 3.402823466e38f

// Pass-1 tiling: CC_N=1 — each block owns 32 consecutive FULL rows, i.e. one
// perfectly contiguous 640 KB extent (the 6.3-6.8 TB/s streaming shape).
// 256 blocks x 640 threads (10 waves); thread owns cols {tid, tid+640}.
#define RC_N   256           // row chunks (RC_N*ROWS == B_SZ)
#define ROWS   32
#define NT1    640           // 10 waves
#define NW1    10            // waves per pass-1 block
#define NPF    2             // rows per ping-pong buffer (x2 cols = 4 ld/thr)
#define NT2    320
#define NFOLD  (K_LAB * 4)   // 40 fold blocks (k, col-quarter)

// loss = sum_{k: n_k>0} (SSQ_k - ||S_k||^2/n_k + n_k*CH*eps^2) / (n_k*CH)
// (2*eps cross-term cancels exactly: sum_{b in k}(z_b - mu_k) == 0)

__device__ __forceinline__ float4 sanitize(float4 v) {
    v.x = (v.x == v.x) ? fminf(fmaxf(v.x, -FLTMAX), FLTMAX) : 0.f;
    v.y = (v.y == v.y) ? fminf(fmaxf(v.y, -FLTMAX), FLTMAX) : 0.f;
    v.z = (v.z == v.z) ? fminf(fmaxf(v.z, -FLTMAX), FLTMAX) : 0.f;
    v.w = (v.w == v.w) ? fminf(fmaxf(v.w, -FLTMAX), FLTMAX) : 0.f;
    return v;
}

// ---------------------------------------------------------------------------
// Pass 1: rows pre-sorted by label (wave-0 ballot) -> one live accumulator,
// zero per-element branches (R7, proven); NEW: block reads a contiguous
// 640 KB extent (whole rows) instead of 5 KB granules at 20 KB period.
// NO __launch_bounds__ min-waves (R3: forcing it spills).
__global__ __launch_bounds__(NT1) void codi_pass1(
    const float4* __restrict__ z4, const int* __restrict__ labels,
    float4* __restrict__ P_sum, float* __restrict__ P_ssq,
    int* __restrict__ P_cnt, int* __restrict__ done)
{
    const int tid  = threadIdx.x;
    const int lane = tid & 63, wid = tid >> 6;
    const int rc   = blockIdx.x;

    __shared__ int   perm_s[ROWS];       // rows in label-grouped ascending order
    __shared__ int   starts_s[K_LAB + 1];
    __shared__ float wssq[NW1][K_LAB];

    if (blockIdx.x == 0 && tid == 0) *done = 0;   // re-init ticket (poisoned ws)
    if (tid < NW1 * K_LAB) ((float*)wssq)[tid] = 0.f;

    // wave 0: label-grouped ascending row order + group starts (ballot trick)
    if (tid < 64) {
        const int lab = (tid < ROWS) ? labels[rc * ROWS + tid] : -1;
        const unsigned long long ltm = (1ULL << lane) - 1ULL;
        int base = 0;
        #pragma unroll
        for (int k = 0; k < K_LAB; ++k) {
            unsigned long long m = __ballot(lab == k);
            int cnt = __popcll(m);
            if (tid == k) {
                starts_s[k] = base;
                P_cnt[rc * K_LAB + k] = cnt;
            }
            if (lab == k) perm_s[base + __popcll(m & ltm)] = tid;
            base += cnt;
        }
        if (tid == 0) starts_s[K_LAB] = ROWS;
    }
    __syncthreads();

    // thread owns float4-cols {tid, tid+640}; block extent fully contiguous
    const float4* zp  = z4 + (size_t)rc * ROWS * CH4 + tid;
    float4*       psb = P_sum + (size_t)rc * CH4 + tid;      // k=0 slot

    float4 cs0 = make_float4(0.f, 0.f, 0.f, 0.f);   // current group's sums
    float4 cs1 = make_float4(0.f, 0.f, 0.f, 0.f);
    float  cq  = 0.f;                               // current group's ssq
    int    kcur = 0;
    int    nb   = starts_s[1];                      // next group boundary

    #define FLUSH() do { \
        psb[(size_t)kcur * RC_N * CH4]       = cs0; \
        psb[(size_t)kcur * RC_N * CH4 + 640] = cs1; \
        float qq = cq; \
        _Pragma("unroll") \
        for (int o = 32; o > 0; o >>= 1) qq += __shfl_down(qq, o, 64); \
        if (lane == 0) wssq[wid][kcur] += qq; \
        cs0 = make_float4(0.f, 0.f, 0.f, 0.f); \
        cs1 = make_float4(0.f, 0.f, 0.f, 0.f); cq = 0.f; \
    } while (0)

    #define LDP(BUF, I0) do { \
        _Pragma("unroll") \
        for (int u = 0; u < NPF; ++u) { \
            const size_t rb_ = (size_t)perm_s[(I0) + u] * CH4; \
            BUF[u][0] = zp[rb_]; \
            BUF[u][1] = zp[rb_ + 640]; \
        } } while (0)

    #define CONS(BUF, I0) do { \
        _Pragma("unroll") \
        for (int u = 0; u < NPF; ++u) { \
            while ((I0) + u >= nb) {          /* uniform, ~10 takes total */ \
                FLUSH(); ++kcur; nb = starts_s[kcur + 1]; \
            } \
            float4 t0 = sanitize(BUF[u][0]); \
            float4 t1 = sanitize(BUF[u][1]); \
            float  q  = fmaf(t0.x, t0.x, fmaf(t0.y, t0.y, \
                        fmaf(t0.z, t0.z, t0.w * t0.w))); \
            q = fmaf(t1.x, t1.x, fmaf(t1.y, t1.y, \
                fmaf(t1.z, t1.z, fmaf(t1.w, t1.w, q)))); \
            cs0.x += t0.x; cs0.y += t0.y; cs0.z += t0.z; cs0.w += t0.w; \
            cs1.x += t1.x; cs1.y += t1.y; cs1.z += t1.z; cs1.w += t1.w; \
            cq += q; \
        } } while (0)

    // ping-pong: B's loads issued before consuming A -> 8 loads in flight
    float4 va[NPF][2], vb[NPF][2];
    LDP(va, 0);
    for (int i = 0; i < ROWS; i += 2 * NPF) {       // 8 iterations, uniform
        LDP(vb, i + NPF);
        CONS(va, i);
        if (i + 2 * NPF < ROWS) LDP(va, i + 2 * NPF);
        CONS(vb, i + NPF);
    }
    for (; kcur < K_LAB; ++kcur) FLUSH();           // trailing (incl. empty)
    #undef CONS
    #undef LDP
    #undef FLUSH

    __syncthreads();
    if (tid < K_LAB) {
        float s = 0.f;
        #pragma unroll
        for (int w = 0; w < NW1; ++w) s += wssq[w][tid];
        P_ssq[rc * K_LAB + tid] = s;
    }
}

// ---------------------------------------------------------------------------
// Pass 2: 40 blocks (k, col-quarter); fold P_sum[k][rc][col] over rc
// (5 KB per rc step, L2/L3-hot), square-reduce to ||S_k||^2 partials;
// q==0 blocks fold SSQ_k and n_k; last-ticket block finalizes the loss.
__global__ __launch_bounds__(NT2) void codi_pass2(
    const float4* __restrict__ P_sum, const float* __restrict__ P_ssq,
    const int* __restrict__ P_cnt, float* __restrict__ pn,
    float* __restrict__ ssqk, float* __restrict__ cntk,
    int* __restrict__ done, float* __restrict__ out)
{
    const int tid  = threadIdx.x;
    const int lane = tid & 63, wid = tid >> 6;
    const int fid  = blockIdx.x;         // 0..39
    const int fk   = fid >> 2, fq = fid & 3;

    __shared__ float red_q[5], red_s[5];
    __shared__ int   red_n[5];
    __shared__ int   tkt;

    const float4* p = P_sum + (size_t)fk * RC_N * CH4 + fq * NT2 + tid;
    float4 s4 = make_float4(0.f, 0.f, 0.f, 0.f);
    #pragma unroll 8
    for (int rc = 0; rc < RC_N; ++rc) {
        float4 v = p[(size_t)rc * CH4];
        s4.x += v.x; s4.y += v.y; s4.z += v.z; s4.w += v.w;
    }
    float q = fmaf(s4.x, s4.x, fmaf(s4.y, s4.y, fmaf(s4.z, s4.z, s4.w * s4.w)));
    #pragma unroll
    for (int o = 32; o > 0; o >>= 1) q += __shfl_down(q, o, 64);

    // SSQ_k and n_k folds (only the fq==0 block of each k)
    float s2 = 0.f;
    int   n  = 0;
    if (fq == 0 && tid < RC_N) {
        s2 = P_ssq[tid * K_LAB + fk];
        n  = P_cnt[tid * K_LAB + fk];
    }
    #pragma unroll
    for (int o = 32; o > 0; o >>= 1) s2 += __shfl_down(s2, o, 64);
    #pragma unroll
    for (int o = 32; o > 0; o >>= 1) n += __shfl_down(n, o, 64);

    if (lane == 0) { red_q[wid] = q; red_s[wid] = s2; red_n[wid] = n; }
    __syncthreads();
    if (tid == 0) {
        pn[fid] = red_q[0] + red_q[1] + red_q[2] + red_q[3] + red_q[4];
        if (fq == 0) {
            ssqk[fk] = red_s[0] + red_s[1] + red_s[2] + red_s[3] + red_s[4];
            cntk[fk] = (float)(red_n[0] + red_n[1] + red_n[2] + red_n[3] + red_n[4]);
        }
    }

    // ---------------- finalize: last block computes the loss
    __threadfence();
    __syncthreads();
    if (tid == 0) tkt = atomicAdd(done, 1);   // tickets 0..39
    __syncthreads();
    if (tkt == NFOLD - 1 && tid < 64) {
        float np4 = (tid < NFOLD) ? atomicAdd(&pn[tid], 0.f) : 0.f;   // coherent
        np4 += __shfl_down(np4, 2, 64);
        np4 += __shfl_down(np4, 1, 64);   // lane 4k holds sum over quarters
        float s2v = (tid < K_LAB) ? atomicAdd(&ssqk[tid], 0.f) : 0.f;
        float nnv = (tid < K_LAB) ? atomicAdd(&cntk[tid], 0.f) : 0.f;
        float acc = 0.f;
        for (int k = 0; k < K_LAB; ++k) {
            float np = __shfl(np4, 4 * k, 64);
            float sk = __shfl(s2v, k, 64);
            float nk = __shfl(nnv, k, 64);
            if (nk > 0.f) {
                float sse = sk - np / nk + nk * (float)CH * (EPS * EPS);
                float mse = sse / (nk * (float)CH);
                if (mse == mse) acc += mse;    // nan_to_num(mse_k)
            }
        }
        if (tid == 0) out[0] = acc;
    }
}

// ---------------------------------------------------------------------------
extern "C" void kernel_launch(void* const* d_in, const int* in_sizes, int n_in,
                              void* d_out, int out_size, void* d_ws, size_t ws_size,
                              hipStream_t stream) {
    const float4* z4     = (const float4*)d_in[0];
    const int*    labels = (const int*)d_in[1];

    // ws layout (float units):
    //   [0] done (int) | [16..56) pn[40] | [64..74) ssqk | [80..90) cntk
    //   [96..2656) P_cnt[2560] (int) | [2688..5248) P_ssq[2560]
    //   [5376..) P_sum: 10*256*1280 float4 = 52.4 MB (byte off 21504, 16B-al;
    //   workspace is >=655 MB per the harness poison-fill size)
    float*  hdr   = (float*)d_ws;
    int*    done  = (int*)hdr;
    float*  pn    = hdr + 16;
    float*  ssqk  = hdr + 64;
    float*  cntk  = hdr + 80;
    int*    P_cnt = (int*)(hdr + 96);
    float*  P_ssq = hdr + 2688;
    float4* P_sum = (float4*)(hdr + 5376);

    codi_pass1<<<RC_N, NT1, 0, stream>>>(z4, labels, P_sum, P_ssq, P_cnt, done);
    codi_pass2<<<NFOLD, NT2, 0, stream>>>(P_sum, P_ssq, P_cnt, pn, ssqk,
                                          cntk, done, (float*)d_out);
}